// Round 7
// baseline (124.104 us; speedup 1.0000x reference)
//
#include <hip/hip_runtime.h>

#define IMG  12
#define NPIX 144            // 12*12
#define IPB  21             // images per block (252 of 256 threads active in compute)
#define XSTR 148            // padded LDS stride (floats) >= NPIX!  16B-aligned (592B); mild bank spread
#define THREADS 256

__global__ __launch_bounds__(THREADS)
void dft_apx_kernel(const float* __restrict__ x,
                    const float* __restrict__ wr,
                    const float* __restrict__ wi,
                    float* __restrict__ out, int size)
{
    // Two physical buffers; bufA holds x during stage 1 loads, then is recycled for rt.
    __shared__ float bufA[IPB * XSTR];   // xs -> rts
    __shared__ float bufB[IPB * XSTR];   // its

    const int tid  = threadIdx.x;
    const int img0 = blockIdx.x * IPB;
    int nimg = size - img0; if (nimg > IPB) nimg = IPB;

    // Quantized weight tables in registers.
    // W[j,k] depends only on (j*k) mod 12; row j=1 of the weight input is exactly
    // that 12-entry table: wr[12+m] = cos(2*pi*m/12)+1e-5, wi[12+m] = -sin(..)+1e-5.
    // approx pass: wq = round(w * (65536-1)); rintf == jnp.round (round-half-even; values far from ties).
    float cq[12], sq[12];
    #pragma unroll
    for (int m = 0; m < 12; ++m) {
        cq[m] = rintf(wr[12 + m] * 65535.0f);   // uniform addr -> scalar loads
        sq[m] = rintf(wi[12 + m] * 65535.0f);
    }

    // ---- stage x into LDS (float4, coalesced; 36 float4 per image, never crosses image) ----
    const float4* xg = (const float4*)(x + (size_t)img0 * NPIX);
    const int n4 = nimg * (NPIX / 4);
    for (int i = tid; i < n4; i += THREADS) {
        const int im = i / 36, e4 = i % 36;
        *(float4*)&bufA[im * XSTR + e4 * 4] = xg[i];
    }
    __syncthreads();

    const int img_l  = tid / IMG;
    const int lane12 = tid - img_l * IMG;
    const bool active = (tid < IPB * IMG) && (img_l < nimg);

    // ---- stage 1a: pull own x column into registers ----
    float xr[12];
    if (active) {
        #pragma unroll
        for (int j = 0; j < 12; ++j)
            xr[j] = bufA[img_l * XSTR + j * IMG + lane12];
    }
    __syncthreads();   // everyone done READING bufA -> safe to overwrite with rt

    // ---- stage 1b: T = (Wq @ x) / 65536 ; thread owns column `lane12` ----
    if (active) {
        #pragma unroll
        for (int r = 0; r < 12; ++r) {
            float ar = 0.0f, ai = 0.0f;
            #pragma unroll
            for (int j = 0; j < 12; ++j) {
                const int m = (r * j) % 12;     // compile-time constant after unroll
                ar = fmaf(cq[m], xr[j], ar);
                ai = fmaf(sq[m], xr[j], ai);
            }
            bufA[img_l * XSTR + r * IMG + lane12] = ar * (1.0f / 65536.0f);
            bufB[img_l * XSTR + r * IMG + lane12] = ai * (1.0f / 65536.0f);
        }
    }
    __syncthreads();

    // ---- stage 2: O = (T @ Wq) / 65536 ; |O| ; thread owns row `lane12` ----
    if (active) {
        float rt[12], it[12];
        // contiguous row -> 3x ds_read_b128 each (16B aligned: XSTR*4=592 and 48 are mult of 16)
        #pragma unroll
        for (int q = 0; q < 3; ++q) {
            float4 a = *(const float4*)&bufA[img_l * XSTR + lane12 * IMG + q * 4];
            float4 b = *(const float4*)&bufB[img_l * XSTR + lane12 * IMG + q * 4];
            rt[q*4+0]=a.x; rt[q*4+1]=a.y; rt[q*4+2]=a.z; rt[q*4+3]=a.w;
            it[q*4+0]=b.x; it[q*4+1]=b.y; it[q*4+2]=b.z; it[q*4+3]=b.w;
        }
        float o[12];
        #pragma unroll
        for (int cc = 0; cc < 12; ++cc) {
            float ro = 0.0f, io = 0.0f;
            #pragma unroll
            for (int j = 0; j < 12; ++j) {
                const int m = (j * cc) % 12;    // compile-time constant after unroll
                ro = fmaf(rt[j],  cq[m], ro);
                ro = fmaf(-it[j], sq[m], ro);   // -v input modifier, free
                io = fmaf(rt[j],  sq[m], io);
                io = fmaf(it[j],  cq[m], io);
            }
            ro *= (1.0f / 65536.0f);
            io *= (1.0f / 65536.0f);
            o[cc] = sqrtf(fmaf(ro, ro, io * io));
        }
        // out offset = 12 * global_thread -> dense; wave covers contiguous 3 KB
        float4* og = (float4*)(out + (size_t)(img0 + img_l) * NPIX + lane12 * IMG);
        og[0] = make_float4(o[0], o[1], o[2],  o[3]);
        og[1] = make_float4(o[4], o[5], o[6],  o[7]);
        og[2] = make_float4(o[8], o[9], o[10], o[11]);
    }
}

extern "C" void kernel_launch(void* const* d_in, const int* in_sizes, int n_in,
                              void* d_out, int out_size, void* d_ws, size_t ws_size,
                              hipStream_t stream) {
    const float* x  = (const float*)d_in[0];   // (1, 100000, 12, 12) f32
    const float* wr = (const float*)d_in[1];   // (1, 144) f32
    const float* wi = (const float*)d_in[2];   // (1, 144) f32
    float* out = (float*)d_out;                // (1,1,100000,12,12) f32

    const int size = in_sizes[0] / NPIX;       // 100000
    const int blocks = (size + IPB - 1) / IPB; // 4762
    dft_apx_kernel<<<blocks, THREADS, 0, stream>>>(x, wr, wi, out, size);
}